// Round 5
// baseline (2682.158 us; speedup 1.0000x reference)
//
#include <hip/hip_runtime.h>
#include <hip/hip_bf16.h>

// GCN 3-layer forward. Round 5: bucket counting-sort edge pipeline (no global atomics,
// near-coalesced placement writes) + per-bucket LDS-accumulator aggregation.
// Layers: S = H@W (bf16 MFMA); H' = relu(agg + b) via bucket LDS scatter-add.

#define EPB 8192   // edges per binning block

__device__ __forceinline__ unsigned short f2bf(float f) {
    unsigned int u = __float_as_uint(f);
    unsigned int r = (u + 0x7fffu + ((u >> 16) & 1u)) >> 16;   // RNE
    return (unsigned short)r;
}

using frag_ab = __attribute__((ext_vector_type(8))) short;   // 8 bf16
using frag_cd = __attribute__((ext_vector_type(4))) float;   // 4 fp32

// ---------------- MFMA GEMM: C[M,BN](bf16) = A[M,K](fp32) @ WT[BN,K](bf16)^T ----------------
template <int BN>
__global__ __launch_bounds__(256) void mfma_gemm_kernel(
    const float* __restrict__ A, const unsigned short* __restrict__ WT,
    unsigned short* __restrict__ C, int M, int K)
{
    constexpr int BM = 64, BK = 64;
    constexpr int LDA = BK + 8;
    __shared__ unsigned short As[BM * LDA];
    __shared__ unsigned short Bs[BN * LDA];

    const int tid = threadIdx.x;
    const int wave = tid >> 6;
    const int lane = tid & 63;
    const int quad = lane >> 4;
    const int l16 = lane & 15;
    const int m0 = blockIdx.x * BM;

    frag_cd acc[BN / 16];
#pragma unroll
    for (int f = 0; f < BN / 16; ++f) acc[f] = (frag_cd){0.f, 0.f, 0.f, 0.f};

    for (int k0 = 0; k0 < K; k0 += BK) {
#pragma unroll
        for (int i = 0; i < 4; ++i) {
            const int linear = (i * 256 + tid) * 4;
            const int r = linear >> 6;
            const int c = linear & 63;
            const int row = m0 + r;
            float4 v = make_float4(0.f, 0.f, 0.f, 0.f);
            if (row < M) v = *(const float4*)&A[(size_t)row * K + k0 + c];
            ushort4 u;
            u.x = f2bf(v.x); u.y = f2bf(v.y); u.z = f2bf(v.z); u.w = f2bf(v.w);
            *(ushort4*)&As[r * LDA + c] = u;
        }
#pragma unroll
        for (int i = 0; i < BN / 32; ++i) {
            const int linear = (i * 256 + tid) * 8;
            const int n = linear >> 6;
            const int c = linear & 63;
            const uint4 u = *(const uint4*)&WT[(size_t)n * K + k0 + c];
            *(uint4*)&Bs[n * LDA + c] = u;
        }
        __syncthreads();

#pragma unroll
        for (int ks = 0; ks < 2; ++ks) {
            const int kk = ks * 32 + quad * 8;
            const frag_ab a = *(const frag_ab*)&As[(wave * 16 + l16) * LDA + kk];
#pragma unroll
            for (int f = 0; f < BN / 16; ++f) {
                const frag_ab b = *(const frag_ab*)&Bs[(f * 16 + l16) * LDA + kk];
                acc[f] = __builtin_amdgcn_mfma_f32_16x16x32_bf16(a, b, acc[f], 0, 0, 0);
            }
        }
        __syncthreads();
    }

#pragma unroll
    for (int f = 0; f < BN / 16; ++f) {
#pragma unroll
        for (int r = 0; r < 4; ++r) {
            const int row = m0 + wave * 16 + quad * 4 + r;
            if (row < M) C[(size_t)row * BN + f * 16 + l16] = f2bf(acc[f][r]);
        }
    }
}

// ---------------- weight transpose+convert ----------------
__global__ __launch_bounds__(256) void wt_kernel(
    const float* __restrict__ W1, const float* __restrict__ W2, const float* __restrict__ W3,
    unsigned short* __restrict__ WT1, unsigned short* __restrict__ WT2, unsigned short* __restrict__ WT3)
{
    const int i = blockIdx.x * 256 + threadIdx.x;
    const float* W; unsigned short* WT; int K, N, j;
    if (i < 32768)      { W = W1; WT = WT1; K = 256; N = 128; j = i; }
    else if (i < 40960) { W = W2; WT = WT2; K = 128; N = 64;  j = i - 32768; }
    else if (i < 45056) { W = W3; WT = WT3; K = 64;  N = 64;  j = i - 40960; }
    else return;
    const int n = j / K, k = j % K;
    WT[j] = f2bf(W[k * N + n]);
}

// ---------------- phase 1: per-block bucket histogram (no global atomics) ----------------
__global__ __launch_bounds__(256) void count_kernel(
    const int* __restrict__ dst, int* __restrict__ cmat, int E, int nblk, int nbuck)
{
    __shared__ int hist[1600];
    for (int i = threadIdx.x; i < nbuck; i += 256) hist[i] = 0;
    __syncthreads();
    const int base = blockIdx.x * EPB;
    const int end = min(base + EPB, E);
    for (int e = base + threadIdx.x; e < end; e += 256)
        atomicAdd(&hist[dst[e] >> 6], 1);
    __syncthreads();
    for (int i = threadIdx.x; i < nbuck; i += 256)
        cmat[(size_t)i * nblk + blockIdx.x] = hist[i];
}

// ---------------- scan: exclusive prefix over cmat (L = nbuck*nblk elems) ----------------
// scanA: 1024 elems/block (256 thr x 4), in-place exclusive, block total -> psum
__global__ __launch_bounds__(256) void scanA_kernel(
    int* __restrict__ data, int* __restrict__ psum, int L)
{
    __shared__ int tmp[256];
    const int b0 = blockIdx.x * 1024 + threadIdx.x * 4;
    int v[4] = {0, 0, 0, 0};
    if (b0 + 3 < L) { const int4 t = *(const int4*)&data[b0]; v[0]=t.x; v[1]=t.y; v[2]=t.z; v[3]=t.w; }
    else { for (int i = 0; i < 4; ++i) if (b0 + i < L) v[i] = data[b0 + i]; }
    const int s = v[0] + v[1] + v[2] + v[3];
    tmp[threadIdx.x] = s;
    __syncthreads();
#pragma unroll
    for (int d = 1; d < 256; d <<= 1) {
        const int t = (threadIdx.x >= d) ? tmp[threadIdx.x - d] : 0;
        __syncthreads();
        tmp[threadIdx.x] += t;
        __syncthreads();
    }
    int run = tmp[threadIdx.x] - s;   // exclusive base for this thread
    int o[4];
#pragma unroll
    for (int i = 0; i < 4; ++i) { o[i] = run; run += v[i]; }
    if (b0 + 3 < L) { *(int4*)&data[b0] = make_int4(o[0], o[1], o[2], o[3]); }
    else { for (int i = 0; i < 4; ++i) if (b0 + i < L) data[b0 + i] = o[i]; }
    if (threadIdx.x == 255) psum[blockIdx.x] = tmp[255];
}

// scanB: single block, exclusive scan of up to 1024 block sums
__global__ __launch_bounds__(1024) void scanB_kernel(int* __restrict__ psum, int nb)
{
    __shared__ int tmp[1024];
    const int v = ((int)threadIdx.x < nb) ? psum[threadIdx.x] : 0;
    tmp[threadIdx.x] = v;
    __syncthreads();
#pragma unroll
    for (int d = 1; d < 1024; d <<= 1) {
        const int t = ((int)threadIdx.x >= d) ? tmp[threadIdx.x - d] : 0;
        __syncthreads();
        tmp[threadIdx.x] += t;
        __syncthreads();
    }
    if ((int)threadIdx.x < nb) psum[threadIdx.x] = tmp[threadIdx.x] - v;
}

// scanC: add scanned block sums back
__global__ __launch_bounds__(256) void scanC_kernel(
    int* __restrict__ data, const int* __restrict__ psum, int L)
{
    const int i = blockIdx.x * 256 + threadIdx.x;
    if (i < L) data[i] += psum[i >> 10];
}

// ---------------- phase 2: placement (LDS cursors, near-coalesced writes) ----------------
// ecsr[pos] = { (src<<6) | (dst&63), bits(w) }, bucket-sorted by dst>>6
__global__ __launch_bounds__(256) void place_kernel(
    const int* __restrict__ src, const int* __restrict__ dst, const float* __restrict__ ew,
    const int* __restrict__ cmat, uint2* __restrict__ ecsr, int E, int nblk, int nbuck)
{
    __shared__ int cursor[1600];
    const int k = blockIdx.x;
    for (int i = threadIdx.x; i < nbuck; i += 256)
        cursor[i] = cmat[(size_t)i * nblk + k];
    __syncthreads();
    const int base = k * EPB;
    const int end = min(base + EPB, E);
    for (int e = base + threadIdx.x; e < end; e += 256) {
        const int d = dst[e];
        const int b = d >> 6;
        const int pos = atomicAdd(&cursor[b], 1);
        ecsr[pos] = make_uint2(((unsigned)src[e] << 6) | (unsigned)(d & 63),
                               __float_as_uint(ew[e]));
    }
}

// ---------------- phase 3: per-bucket LDS aggregation + bias + relu ----------------
// D=128: 16 lanes/edge (4 edges/wave); D=64: 8 lanes/edge (8 edges/wave).
// LDS layout acc[q][node][ll] (q = channel&7 within lane's 8) -> <=2-way bank conflicts.
template <int D, bool RELU>
__global__ __launch_bounds__(256) void agg_kernel(
    const unsigned short* __restrict__ S, const int* __restrict__ cmat,
    const uint2* __restrict__ ecsr, const float* __restrict__ bias,
    float* __restrict__ out, int N, int nblk, int nbuck, int E)
{
    constexpr int LPE = D / 8;        // lanes per edge
    constexpr int ACC = D * 64;
    __shared__ float acc[ACC];
    const int b = blockIdx.x;

    for (int i = threadIdx.x; i < ACC; i += 256) acc[i] = 0.f;
    __syncthreads();

    const int j0 = cmat[(size_t)b * nblk];
    const int j1 = (b + 1 < nbuck) ? cmat[(size_t)(b + 1) * nblk] : E;

    const int wave = threadIdx.x >> 6;
    const int lane = threadIdx.x & 63;
    const int esub = lane / LPE;      // edge slot within wave
    const int ll = lane % LPE;        // sub-lane within edge

    for (int c0 = j0 + wave * 64; c0 < j1; c0 += 256) {
        const int cnt = min(64, j1 - c0);
        uint2 ed = make_uint2(0u, 0u);
        if (lane < cnt) ed = ecsr[c0 + lane];
#pragma unroll 4
        for (int t = 0; t < LPE; ++t) {
            const int eidx = esub * LPE + t;
            if (eidx >= cnt) continue;                    // uniform per LPE-group
            const unsigned pk = (unsigned)__shfl((int)ed.x, eidx, 64);
            const float w = __uint_as_float(__shfl((int)ed.y, eidx, 64));
            const int s = (int)(pk >> 6);
            const int dl = (int)(pk & 63u);
            const uint4 v = *(const uint4*)&S[(size_t)s * D + ll * 8];
#pragma unroll
            for (int p = 0; p < 4; ++p) {
                const unsigned u = (&v.x)[p];
                const float lo = __uint_as_float(u << 16);
                const float hi = __uint_as_float(u & 0xffff0000u);
                // channel = ll*8 + 2p (+1); LDS addr = q*(64*LPE) + dl*LPE + ll
                atomicAdd(&acc[(2 * p + 0) * (64 * LPE) + dl * LPE + ll], w * lo);
                atomicAdd(&acc[(2 * p + 1) * (64 * LPE) + dl * LPE + ll], w * hi);
            }
        }
    }
    __syncthreads();

    // epilogue: node n (0..63), channel c; acc addr = (c&7)*(64*LPE) + n*LPE + (c>>3)
    const int node0 = b << 6;
    for (int i = threadIdx.x; i < 16 * D; i += 256) {     // (64*D)/4 float4 stores
        const int n = i / (D / 4);
        const int c4 = (i % (D / 4)) * 4;
        const int node = node0 + n;
        if (node >= N) continue;
        float4 o;
        float* po = &o.x;
#pragma unroll
        for (int q2 = 0; q2 < 4; ++q2) {
            const int c = c4 + q2;
            float val = acc[(c & 7) * (64 * LPE) + n * LPE + (c >> 3)] + bias[c];
            if (RELU) val = fmaxf(val, 0.f);
            po[q2] = val;
        }
        *(float4*)&out[(size_t)node * D + c4] = o;
    }
}

extern "C" void kernel_launch(void* const* d_in, const int* in_sizes, int n_in,
                              void* d_out, int out_size, void* d_ws, size_t ws_size,
                              hipStream_t stream)
{
    const float* x    = (const float*)d_in[0];
    const int*   esrc = (const int*)  d_in[1];
    const int*   edst = (const int*)  d_in[2];
    const float* ew   = (const float*)d_in[3];
    const float* W1   = (const float*)d_in[4];
    const float* b1   = (const float*)d_in[5];
    const float* W2   = (const float*)d_in[6];
    const float* b2   = (const float*)d_in[7];
    const float* W3   = (const float*)d_in[8];
    const float* b3   = (const float*)d_in[9];

    const int N = in_sizes[0] / 256;   // 100000
    const int E = in_sizes[1];         // 1600000

    const int nbuck = (N + 63) >> 6;               // 1563
    const int nblk = (E + EPB - 1) / EPB;          // 196
    const int L = nbuck * nblk;                    // ~306K

    // workspace layout (16B-aligned sections)
    unsigned short* Sb = (unsigned short*)d_ws;            // N*128 bf16 support
    float* H   = (float*)(Sb + (size_t)N * 128);           // N*128 fp32 hidden
    unsigned short* WT1 = (unsigned short*)(H + (size_t)N * 128);  // 32768
    unsigned short* WT2 = WT1 + 256 * 128;                 // 8192
    unsigned short* WT3 = WT2 + 128 * 64;                  // 4096
    uint2* ecsr = (uint2*)(WT3 + 64 * 64);                 // E packed (src|dstlow, w)
    int* cmat   = (int*)(ecsr + E);                        // nbuck*nblk
    int* psum   = cmat + ((L + 3) & ~3);                   // up to 1024
    float* out  = (float*)d_out;

    const dim3 blk(256);
    const int mblocks = (N + 63) / 64;                     // 1563

    // ---- prep: weights + bucket counting sort ----
    wt_kernel<<<(45056 + 255) / 256, blk, 0, stream>>>(W1, W2, W3, WT1, WT2, WT3);
    count_kernel<<<nblk, blk, 0, stream>>>(edst, cmat, E, nblk, nbuck);
    scanA_kernel<<<(L + 1023) / 1024, blk, 0, stream>>>(cmat, psum, L);
    scanB_kernel<<<1, 1024, 0, stream>>>(psum, (L + 1023) / 1024);
    scanC_kernel<<<(L + 255) / 256, blk, 0, stream>>>(cmat, psum, L);
    place_kernel<<<nblk, blk, 0, stream>>>(esrc, edst, ew, cmat, ecsr, E, nblk, nbuck);

    // ---- layer 1: 256 -> 128 ----
    mfma_gemm_kernel<128><<<mblocks, blk, 0, stream>>>(x, WT1, Sb, N, 256);
    agg_kernel<128, true><<<nbuck, blk, 0, stream>>>(Sb, cmat, ecsr, b1, H, N, nblk, nbuck, E);

    // ---- layer 2: 128 -> 64 ----
    mfma_gemm_kernel<64><<<mblocks, blk, 0, stream>>>(H, WT2, Sb, N, 128);
    agg_kernel<64, true><<<nbuck, blk, 0, stream>>>(Sb, cmat, ecsr, b2, H, N, nblk, nbuck, E);

    // ---- layer 3: 64 -> 64 ----
    mfma_gemm_kernel<64><<<mblocks, blk, 0, stream>>>(H, WT3, Sb, N, 64);
    agg_kernel<64, false><<<nbuck, blk, 0, stream>>>(Sb, cmat, ecsr, b3, out, N, nblk, nbuck, E);
}

// Round 6
// 520.278 us; speedup vs baseline: 5.1552x; 5.1552x over previous
//
#include <hip/hip_runtime.h>
#include <hip/hip_bf16.h>

// GCN 3-layer forward. Round 6: round-4 pipeline (MFMA GEMM + per-node CSR register-
// accumulate gather) with the CSR fill replaced by a two-phase locality sort:
//   count/scan -> place (bucket-sorted, near-coalesced) -> sort2 (per-bucket LDS cursors,
//   writes confined to the bucket's 8KB window -> full lines in L2).

#define EPB 8192   // edges per binning block

__device__ __forceinline__ unsigned short f2bf(float f) {
    unsigned int u = __float_as_uint(f);
    unsigned int r = (u + 0x7fffu + ((u >> 16) & 1u)) >> 16;   // RNE
    return (unsigned short)r;
}

using frag_ab = __attribute__((ext_vector_type(8))) short;   // 8 bf16
using frag_cd = __attribute__((ext_vector_type(4))) float;   // 4 fp32

// ---------------- MFMA GEMM: C[M,BN](bf16) = A[M,K](fp32) @ WT[BN,K](bf16)^T ----------------
template <int BN>
__global__ __launch_bounds__(256) void mfma_gemm_kernel(
    const float* __restrict__ A, const unsigned short* __restrict__ WT,
    unsigned short* __restrict__ C, int M, int K)
{
    constexpr int BM = 64, BK = 64;
    constexpr int LDA = BK + 8;
    __shared__ unsigned short As[BM * LDA];
    __shared__ unsigned short Bs[BN * LDA];

    const int tid = threadIdx.x;
    const int wave = tid >> 6;
    const int lane = tid & 63;
    const int quad = lane >> 4;
    const int l16 = lane & 15;
    const int m0 = blockIdx.x * BM;

    frag_cd acc[BN / 16];
#pragma unroll
    for (int f = 0; f < BN / 16; ++f) acc[f] = (frag_cd){0.f, 0.f, 0.f, 0.f};

    for (int k0 = 0; k0 < K; k0 += BK) {
#pragma unroll
        for (int i = 0; i < 4; ++i) {
            const int linear = (i * 256 + tid) * 4;
            const int r = linear >> 6;
            const int c = linear & 63;
            const int row = m0 + r;
            float4 v = make_float4(0.f, 0.f, 0.f, 0.f);
            if (row < M) v = *(const float4*)&A[(size_t)row * K + k0 + c];
            ushort4 u;
            u.x = f2bf(v.x); u.y = f2bf(v.y); u.z = f2bf(v.z); u.w = f2bf(v.w);
            *(ushort4*)&As[r * LDA + c] = u;
        }
#pragma unroll
        for (int i = 0; i < BN / 32; ++i) {
            const int linear = (i * 256 + tid) * 8;
            const int n = linear >> 6;
            const int c = linear & 63;
            const uint4 u = *(const uint4*)&WT[(size_t)n * K + k0 + c];
            *(uint4*)&Bs[n * LDA + c] = u;
        }
        __syncthreads();

#pragma unroll
        for (int ks = 0; ks < 2; ++ks) {
            const int kk = ks * 32 + quad * 8;
            const frag_ab a = *(const frag_ab*)&As[(wave * 16 + l16) * LDA + kk];
#pragma unroll
            for (int f = 0; f < BN / 16; ++f) {
                const frag_ab b = *(const frag_ab*)&Bs[(f * 16 + l16) * LDA + kk];
                acc[f] = __builtin_amdgcn_mfma_f32_16x16x32_bf16(a, b, acc[f], 0, 0, 0);
            }
        }
        __syncthreads();
    }

#pragma unroll
    for (int f = 0; f < BN / 16; ++f) {
#pragma unroll
        for (int r = 0; r < 4; ++r) {
            const int row = m0 + wave * 16 + quad * 4 + r;
            if (row < M) C[(size_t)row * BN + f * 16 + l16] = f2bf(acc[f][r]);
        }
    }
}

// ---------------- weight transpose+convert ----------------
__global__ __launch_bounds__(256) void wt_kernel(
    const float* __restrict__ W1, const float* __restrict__ W2, const float* __restrict__ W3,
    unsigned short* __restrict__ WT1, unsigned short* __restrict__ WT2, unsigned short* __restrict__ WT3)
{
    const int i = blockIdx.x * 256 + threadIdx.x;
    const float* W; unsigned short* WT; int K, N, j;
    if (i < 32768)      { W = W1; WT = WT1; K = 256; N = 128; j = i; }
    else if (i < 40960) { W = W2; WT = WT2; K = 128; N = 64;  j = i - 32768; }
    else if (i < 45056) { W = W3; WT = WT3; K = 64;  N = 64;  j = i - 40960; }
    else return;
    const int n = j / K, k = j % K;
    WT[j] = f2bf(W[k * N + n]);
}

// ---------------- per-node degree histogram + scan -> offs ----------------
__global__ __launch_bounds__(256) void zero_int_kernel(int* __restrict__ p, int n)
{
    const int i = blockIdx.x * 256 + threadIdx.x;
    if (i < n) p[i] = 0;
}

__global__ __launch_bounds__(256) void hist_kernel(
    const int* __restrict__ dst, int* __restrict__ deg, int E)
{
    const int e = blockIdx.x * 256 + threadIdx.x;
    if (e < E) atomicAdd(&deg[dst[e]], 1);
}

__global__ __launch_bounds__(256) void scan1_kernel(
    const int* __restrict__ deg, int* __restrict__ offs, int* __restrict__ bsum, int n)
{
    __shared__ int tmp[256];
    const int i = blockIdx.x * 256 + threadIdx.x;
    const int v = (i < n) ? deg[i] : 0;
    tmp[threadIdx.x] = v;
    __syncthreads();
#pragma unroll
    for (int d = 1; d < 256; d <<= 1) {
        const int t = (threadIdx.x >= d) ? tmp[threadIdx.x - d] : 0;
        __syncthreads();
        tmp[threadIdx.x] += t;
        __syncthreads();
    }
    if (i < n) offs[i] = tmp[threadIdx.x] - v;
    if (threadIdx.x == 255) bsum[blockIdx.x] = tmp[255];
}

__global__ __launch_bounds__(512) void scan2_kernel(int* __restrict__ bsum, int nb)
{
    __shared__ int tmp[512];
    const int v = ((int)threadIdx.x < nb) ? bsum[threadIdx.x] : 0;
    tmp[threadIdx.x] = v;
    __syncthreads();
#pragma unroll
    for (int d = 1; d < 512; d <<= 1) {
        const int t = ((int)threadIdx.x >= d) ? tmp[threadIdx.x - d] : 0;
        __syncthreads();
        tmp[threadIdx.x] += t;
        __syncthreads();
    }
    if ((int)threadIdx.x < nb) bsum[threadIdx.x] = tmp[threadIdx.x] - v;
}

__global__ __launch_bounds__(256) void scan3_kernel(
    int* __restrict__ offs, const int* __restrict__ bsum, int n, int E)
{
    const int i = blockIdx.x * 256 + threadIdx.x;
    if (i < n) offs[i] += bsum[blockIdx.x];
    if (i == 0) offs[n] = E;
}

// ---------------- bucket counting sort phase 1: per-block bucket histogram ----------------
__global__ __launch_bounds__(256) void count_kernel(
    const int* __restrict__ dst, int* __restrict__ cmat, int E, int nblk, int nbuck)
{
    __shared__ int hist[1600];
    for (int i = threadIdx.x; i < nbuck; i += 256) hist[i] = 0;
    __syncthreads();
    const int base = blockIdx.x * EPB;
    const int end = min(base + EPB, E);
    for (int e = base + threadIdx.x; e < end; e += 256)
        atomicAdd(&hist[dst[e] >> 6], 1);
    __syncthreads();
    for (int i = threadIdx.x; i < nbuck; i += 256)
        cmat[(size_t)i * nblk + blockIdx.x] = hist[i];
}

// scanA: 1024 elems/block, in-place exclusive, block total -> psum
__global__ __launch_bounds__(256) void scanA_kernel(
    int* __restrict__ data, int* __restrict__ psum, int L)
{
    __shared__ int tmp[256];
    const int b0 = blockIdx.x * 1024 + threadIdx.x * 4;
    int v[4] = {0, 0, 0, 0};
    if (b0 + 3 < L) { const int4 t = *(const int4*)&data[b0]; v[0]=t.x; v[1]=t.y; v[2]=t.z; v[3]=t.w; }
    else { for (int i = 0; i < 4; ++i) if (b0 + i < L) v[i] = data[b0 + i]; }
    const int s = v[0] + v[1] + v[2] + v[3];
    tmp[threadIdx.x] = s;
    __syncthreads();
#pragma unroll
    for (int d = 1; d < 256; d <<= 1) {
        const int t = (threadIdx.x >= d) ? tmp[threadIdx.x - d] : 0;
        __syncthreads();
        tmp[threadIdx.x] += t;
        __syncthreads();
    }
    int run = tmp[threadIdx.x] - s;
    int o[4];
#pragma unroll
    for (int i = 0; i < 4; ++i) { o[i] = run; run += v[i]; }
    if (b0 + 3 < L) { *(int4*)&data[b0] = make_int4(o[0], o[1], o[2], o[3]); }
    else { for (int i = 0; i < 4; ++i) if (b0 + i < L) data[b0 + i] = o[i]; }
    if (threadIdx.x == 255) psum[blockIdx.x] = tmp[255];
}

__global__ __launch_bounds__(1024) void scanB_kernel(int* __restrict__ psum, int nb)
{
    __shared__ int tmp[1024];
    const int v = ((int)threadIdx.x < nb) ? psum[threadIdx.x] : 0;
    tmp[threadIdx.x] = v;
    __syncthreads();
#pragma unroll
    for (int d = 1; d < 1024; d <<= 1) {
        const int t = ((int)threadIdx.x >= d) ? tmp[threadIdx.x - d] : 0;
        __syncthreads();
        tmp[threadIdx.x] += t;
        __syncthreads();
    }
    if ((int)threadIdx.x < nb) psum[threadIdx.x] = tmp[threadIdx.x] - v;
}

__global__ __launch_bounds__(256) void scanC_kernel(
    int* __restrict__ data, const int* __restrict__ psum, int L)
{
    const int i = blockIdx.x * 256 + threadIdx.x;
    if (i < L) data[i] += psum[i >> 10];
}

// ---------------- phase 2: bucket placement (LDS cursors, near-coalesced writes) ----------------
// ebuck[pos] = { (src<<6) | (dst&63), bits(w) }, sorted by bucket = dst>>6
__global__ __launch_bounds__(256) void place_kernel(
    const int* __restrict__ src, const int* __restrict__ dst, const float* __restrict__ ew,
    const int* __restrict__ cmat, uint2* __restrict__ ebuck, int E, int nblk, int nbuck)
{
    __shared__ int cursor[1600];
    const int k = blockIdx.x;
    for (int i = threadIdx.x; i < nbuck; i += 256)
        cursor[i] = cmat[(size_t)i * nblk + k];
    __syncthreads();
    const int base = k * EPB;
    const int end = min(base + EPB, E);
    for (int e = base + threadIdx.x; e < end; e += 256) {
        const int d = dst[e];
        const int b = d >> 6;
        const int pos = atomicAdd(&cursor[b], 1);
        ebuck[pos] = make_uint2(((unsigned)src[e] << 6) | (unsigned)(d & 63),
                                __float_as_uint(ew[e]));
    }
}

// ---------------- phase 3: within-bucket sort to per-node CSR order ----------------
// One block per bucket; cursors = offs[node] in LDS; writes confined to the bucket's
// own output window (avg 8KB) -> every line fully written while resident in L2.
__global__ __launch_bounds__(256) void sort2_kernel(
    const uint2* __restrict__ ebuck, const int* __restrict__ offs,
    uint2* __restrict__ ecsr, int N)
{
    __shared__ int cur[64];
    const int b = blockIdx.x;
    const int node0 = b << 6;
    const int nn = min(64, N - node0);
    if ((int)threadIdx.x < nn) cur[threadIdx.x] = offs[node0 + threadIdx.x];
    __syncthreads();
    const int j0 = offs[node0];
    const int j1 = offs[node0 + nn];   // == offs[min(node0+64, N)]
    for (int j = j0 + (int)threadIdx.x; j < j1; j += 256) {
        const uint2 ed = ebuck[j];
        const int dl = (int)(ed.x & 63u);
        const int pos = atomicAdd(&cur[dl], 1);
        ecsr[pos] = make_uint2(ed.x >> 6, ed.y);
    }
}

// ---------------- fused gather-aggregate (bf16 S) + bias + relu (fp32 out) ----------------
template <int D, int LOGT, bool RELU>
__global__ __launch_bounds__(256) void gather_agg_kernel(
    const unsigned short* __restrict__ S, const int* __restrict__ offs,
    const uint2* __restrict__ ecsr,
    const float* __restrict__ bias, float* __restrict__ out, int N)
{
    const int TPN = 1 << LOGT;
    const int gid = blockIdx.x * 256 + threadIdx.x;
    const int node = gid >> LOGT;
    if (node >= N) return;
    const int lane = gid & (TPN - 1);
    const int c8 = lane << 3;

    const int j0 = offs[node];
    const int j1 = offs[node + 1];

    float acc[8];
#pragma unroll
    for (int c = 0; c < 8; ++c) acc[c] = 0.f;

    for (int jb = j0; jb < j1; jb += TPN) {
        const int j = jb + lane;
        int myc = 0;
        float myw = 0.f;
        if (j < j1) {
            const uint2 p = ecsr[j];
            myc = (int)p.x;
            myw = __uint_as_float(p.y);
        }
        const int cnt = min(TPN, j1 - jb);
        for (int t = 0; t < cnt; ++t) {
            const int s = __shfl(myc, t, TPN);
            const float w = __shfl(myw, t, TPN);
            const uint4 v = *(const uint4*)&S[(size_t)s * D + c8];
#pragma unroll
            for (int q = 0; q < 4; ++q) {
                const unsigned int u = (&v.x)[q];
                const float lo = __uint_as_float(u << 16);
                const float hi = __uint_as_float(u & 0xffff0000u);
                acc[q * 2 + 0] += w * lo;
                acc[q * 2 + 1] += w * hi;
            }
        }
    }

#pragma unroll
    for (int c = 0; c < 8; ++c) {
        float v = acc[c] + bias[c8 + c];
        if (RELU) v = fmaxf(v, 0.f);
        acc[c] = v;
    }
    float4* op = (float4*)&out[(size_t)node * D + c8];
    op[0] = make_float4(acc[0], acc[1], acc[2], acc[3]);
    op[1] = make_float4(acc[4], acc[5], acc[6], acc[7]);
}

extern "C" void kernel_launch(void* const* d_in, const int* in_sizes, int n_in,
                              void* d_out, int out_size, void* d_ws, size_t ws_size,
                              hipStream_t stream)
{
    const float* x    = (const float*)d_in[0];
    const int*   esrc = (const int*)  d_in[1];
    const int*   edst = (const int*)  d_in[2];
    const float* ew   = (const float*)d_in[3];
    const float* W1   = (const float*)d_in[4];
    const float* b1   = (const float*)d_in[5];
    const float* W2   = (const float*)d_in[6];
    const float* b2   = (const float*)d_in[7];
    const float* W3   = (const float*)d_in[8];
    const float* b3   = (const float*)d_in[9];

    const int N = in_sizes[0] / 256;   // 100000
    const int E = in_sizes[1];         // 1600000

    const int nbuck = (N + 63) >> 6;               // 1563
    const int nblk = (E + EPB - 1) / EPB;          // 196
    const int L = nbuck * nblk;

    // workspace layout
    unsigned short* Sb = (unsigned short*)d_ws;            // N*128 bf16 support
    float* H   = (float*)(Sb + (size_t)N * 128);           // N*128 fp32 hidden
    unsigned short* WT1 = (unsigned short*)(H + (size_t)N * 128);
    unsigned short* WT2 = WT1 + 256 * 128;
    unsigned short* WT3 = WT2 + 128 * 64;
    uint2* ebuck = (uint2*)(WT3 + 64 * 64);                // E bucket-sorted
    uint2* ecsr  = ebuck + E;                              // E fully sorted (src, w)
    int* deg    = (int*)(ecsr + E);                        // N
    int* offs   = deg + N;                                 // N+1 (pad 4)
    int* bsum   = offs + N + 4;                            // 512
    int* cmat   = bsum + 512;                              // nbuck*nblk
    int* psum   = cmat + ((L + 3) & ~3);                   // up to 1024
    float* out  = (float*)d_out;

    const dim3 blk(256);
    const int nblkN = (N + 255) / 256;
    const int nblkE = (E + 255) / 256;
    const int mblocks = (N + 63) / 64;

    // ---- prep: weights + per-node offs + bucket sort ----
    wt_kernel<<<(45056 + 255) / 256, blk, 0, stream>>>(W1, W2, W3, WT1, WT2, WT3);
    zero_int_kernel<<<nblkN, blk, 0, stream>>>(deg, N);
    hist_kernel<<<nblkE, blk, 0, stream>>>(edst, deg, E);
    scan1_kernel<<<nblkN, blk, 0, stream>>>(deg, offs, bsum, N);
    scan2_kernel<<<1, 512, 0, stream>>>(bsum, nblkN);
    scan3_kernel<<<nblkN, blk, 0, stream>>>(offs, bsum, N, E);
    count_kernel<<<nblk, blk, 0, stream>>>(edst, cmat, E, nblk, nbuck);
    scanA_kernel<<<(L + 1023) / 1024, blk, 0, stream>>>(cmat, psum, L);
    scanB_kernel<<<1, 1024, 0, stream>>>(psum, (L + 1023) / 1024);
    scanC_kernel<<<(L + 255) / 256, blk, 0, stream>>>(cmat, psum, L);
    place_kernel<<<nblk, blk, 0, stream>>>(esrc, edst, ew, cmat, ebuck, E, nblk, nbuck);
    sort2_kernel<<<nbuck, blk, 0, stream>>>(ebuck, offs, ecsr, N);

    // ---- layer 1: 256 -> 128 ----
    mfma_gemm_kernel<128><<<mblocks, blk, 0, stream>>>(x, WT1, Sb, N, 256);
    gather_agg_kernel<128, 4, true><<<((N * 16) + 255) / 256, blk, 0, stream>>>(
        Sb, offs, ecsr, b1, H, N);

    // ---- layer 2: 128 -> 64 ----
    mfma_gemm_kernel<64><<<mblocks, blk, 0, stream>>>(H, WT2, Sb, N, 128);
    gather_agg_kernel<64, 3, true><<<((N * 8) + 255) / 256, blk, 0, stream>>>(
        Sb, offs, ecsr, b2, H, N);

    // ---- layer 3: 64 -> 64 ----
    mfma_gemm_kernel<64><<<mblocks, blk, 0, stream>>>(H, WT3, Sb, N, 64);
    gather_agg_kernel<64, 3, false><<<((N * 8) + 255) / 256, blk, 0, stream>>>(
        Sb, offs, ecsr, b3, out, N);
}

// Round 7
// 464.966 us; speedup vs baseline: 5.7685x; 1.1190x over previous
//
#include <hip/hip_runtime.h>
#include <hip/hip_bf16.h>

// GCN 3-layer forward. Round 7:
//  - per-node offs computed inside sort2 (bucket LDS hist + wave scan) -> zero/hist/scan1/2/3 deleted
//  - MFMA GEMM BM=128 (2 row-tiles per wave): 2x MFMA per staged byte
//  - gather inner loop: unrolled full-chunk body + tail

#define EPB 8192   // edges per binning block

__device__ __forceinline__ unsigned short f2bf(float f) {
    unsigned int u = __float_as_uint(f);
    unsigned int r = (u + 0x7fffu + ((u >> 16) & 1u)) >> 16;   // RNE
    return (unsigned short)r;
}

using frag_ab = __attribute__((ext_vector_type(8))) short;   // 8 bf16
using frag_cd = __attribute__((ext_vector_type(4))) float;   // 4 fp32

// ---------------- MFMA GEMM: C[M,BN](bf16) = A[M,K](fp32) @ WT[BN,K](bf16)^T ----------------
// BM=128, BK=64; 4 waves, wave w owns rows [w*32, w*32+32) as two 16-row tiles.
template <int BN>
__global__ __launch_bounds__(256) void mfma_gemm_kernel(
    const float* __restrict__ A, const unsigned short* __restrict__ WT,
    unsigned short* __restrict__ C, int M, int K)
{
    constexpr int BM = 128, BK = 64;
    constexpr int LDA = BK + 8;                    // 72: +16B pad, 2-way LDS conflict (free)
    __shared__ unsigned short As[BM * LDA];
    __shared__ unsigned short Bs[BN * LDA];

    const int tid = threadIdx.x;
    const int wave = tid >> 6;
    const int lane = tid & 63;
    const int quad = lane >> 4;
    const int l16 = lane & 15;
    const int m0 = blockIdx.x * BM;

    frag_cd acc[2][BN / 16];
#pragma unroll
    for (int rt = 0; rt < 2; ++rt)
#pragma unroll
        for (int f = 0; f < BN / 16; ++f) acc[rt][f] = (frag_cd){0.f, 0.f, 0.f, 0.f};

    for (int k0 = 0; k0 < K; k0 += BK) {
        // stage A tile (128x64 fp32 -> bf16): 8 float4 per thread
#pragma unroll
        for (int i = 0; i < 8; ++i) {
            const int linear = (i * 256 + tid) * 4;
            const int r = linear >> 6;
            const int c = linear & 63;
            const int row = m0 + r;
            float4 v = make_float4(0.f, 0.f, 0.f, 0.f);
            if (row < M) v = *(const float4*)&A[(size_t)row * K + k0 + c];
            ushort4 u;
            u.x = f2bf(v.x); u.y = f2bf(v.y); u.z = f2bf(v.z); u.w = f2bf(v.w);
            *(ushort4*)&As[r * LDA + c] = u;
        }
        // stage B tile (BN x 64 bf16): BN/32 uint4 per thread
#pragma unroll
        for (int i = 0; i < BN / 32; ++i) {
            const int linear = (i * 256 + tid) * 8;
            const int n = linear >> 6;
            const int c = linear & 63;
            const uint4 u = *(const uint4*)&WT[(size_t)n * K + k0 + c];
            *(uint4*)&Bs[n * LDA + c] = u;
        }
        __syncthreads();

#pragma unroll
        for (int ks = 0; ks < 2; ++ks) {
            const int kk = ks * 32 + quad * 8;
            const frag_ab a0 = *(const frag_ab*)&As[(wave * 32 + l16) * LDA + kk];
            const frag_ab a1 = *(const frag_ab*)&As[(wave * 32 + 16 + l16) * LDA + kk];
#pragma unroll
            for (int f = 0; f < BN / 16; ++f) {
                const frag_ab b = *(const frag_ab*)&Bs[(f * 16 + l16) * LDA + kk];
                acc[0][f] = __builtin_amdgcn_mfma_f32_16x16x32_bf16(a0, b, acc[0][f], 0, 0, 0);
                acc[1][f] = __builtin_amdgcn_mfma_f32_16x16x32_bf16(a1, b, acc[1][f], 0, 0, 0);
            }
        }
        __syncthreads();
    }

#pragma unroll
    for (int rt = 0; rt < 2; ++rt)
#pragma unroll
        for (int f = 0; f < BN / 16; ++f)
#pragma unroll
            for (int r = 0; r < 4; ++r) {
                const int row = m0 + wave * 32 + rt * 16 + quad * 4 + r;
                if (row < M) C[(size_t)row * BN + f * 16 + l16] = f2bf(acc[rt][f][r]);
            }
}

// ---------------- weight transpose+convert ----------------
__global__ __launch_bounds__(256) void wt_kernel(
    const float* __restrict__ W1, const float* __restrict__ W2, const float* __restrict__ W3,
    unsigned short* __restrict__ WT1, unsigned short* __restrict__ WT2, unsigned short* __restrict__ WT3)
{
    const int i = blockIdx.x * 256 + threadIdx.x;
    const float* W; unsigned short* WT; int K, N, j;
    if (i < 32768)      { W = W1; WT = WT1; K = 256; N = 128; j = i; }
    else if (i < 40960) { W = W2; WT = WT2; K = 128; N = 64;  j = i - 32768; }
    else if (i < 45056) { W = W3; WT = WT3; K = 64;  N = 64;  j = i - 40960; }
    else return;
    const int n = j / K, k = j % K;
    WT[j] = f2bf(W[k * N + n]);
}

// ---------------- phase 1: per-block bucket histogram (LDS atomics only) ----------------
__global__ __launch_bounds__(256) void count_kernel(
    const int* __restrict__ dst, int* __restrict__ cmat, int E, int nblk, int nbuck)
{
    __shared__ int hist[1600];
    for (int i = threadIdx.x; i < nbuck; i += 256) hist[i] = 0;
    __syncthreads();
    const int base = blockIdx.x * EPB;
    const int end = min(base + EPB, E);
    for (int e = base + threadIdx.x; e < end; e += 256)
        atomicAdd(&hist[dst[e] >> 6], 1);
    __syncthreads();
    for (int i = threadIdx.x; i < nbuck; i += 256)
        cmat[(size_t)i * nblk + blockIdx.x] = hist[i];
}

// ---------------- scan over cmat (L = nbuck*nblk) ----------------
__global__ __launch_bounds__(256) void scanA_kernel(
    int* __restrict__ data, int* __restrict__ psum, int L)
{
    __shared__ int tmp[256];
    const int b0 = blockIdx.x * 1024 + threadIdx.x * 4;
    int v[4] = {0, 0, 0, 0};
    if (b0 + 3 < L) { const int4 t = *(const int4*)&data[b0]; v[0]=t.x; v[1]=t.y; v[2]=t.z; v[3]=t.w; }
    else { for (int i = 0; i < 4; ++i) if (b0 + i < L) v[i] = data[b0 + i]; }
    const int s = v[0] + v[1] + v[2] + v[3];
    tmp[threadIdx.x] = s;
    __syncthreads();
#pragma unroll
    for (int d = 1; d < 256; d <<= 1) {
        const int t = (threadIdx.x >= d) ? tmp[threadIdx.x - d] : 0;
        __syncthreads();
        tmp[threadIdx.x] += t;
        __syncthreads();
    }
    int run = tmp[threadIdx.x] - s;
    int o[4];
#pragma unroll
    for (int i = 0; i < 4; ++i) { o[i] = run; run += v[i]; }
    if (b0 + 3 < L) { *(int4*)&data[b0] = make_int4(o[0], o[1], o[2], o[3]); }
    else { for (int i = 0; i < 4; ++i) if (b0 + i < L) data[b0 + i] = o[i]; }
    if (threadIdx.x == 255) psum[blockIdx.x] = tmp[255];
}

__global__ __launch_bounds__(1024) void scanB_kernel(int* __restrict__ psum, int nb)
{
    __shared__ int tmp[1024];
    const int v = ((int)threadIdx.x < nb) ? psum[threadIdx.x] : 0;
    tmp[threadIdx.x] = v;
    __syncthreads();
#pragma unroll
    for (int d = 1; d < 1024; d <<= 1) {
        const int t = ((int)threadIdx.x >= d) ? tmp[threadIdx.x - d] : 0;
        __syncthreads();
        tmp[threadIdx.x] += t;
        __syncthreads();
    }
    if ((int)threadIdx.x < nb) psum[threadIdx.x] = tmp[threadIdx.x] - v;
}

__global__ __launch_bounds__(256) void scanC_kernel(
    int* __restrict__ data, const int* __restrict__ psum, int L)
{
    const int i = blockIdx.x * 256 + threadIdx.x;
    if (i < L) data[i] += psum[i >> 10];
}

// ---------------- phase 2: bucket placement (LDS cursors, near-coalesced writes) ----------------
// ebuck[pos] = { (src<<6) | (dst&63), bits(w) }, sorted by bucket = dst>>6
__global__ __launch_bounds__(256) void place_kernel(
    const int* __restrict__ src, const int* __restrict__ dst, const float* __restrict__ ew,
    const int* __restrict__ cmat, uint2* __restrict__ ebuck, int E, int nblk, int nbuck)
{
    __shared__ int cursor[1600];
    const int k = blockIdx.x;
    for (int i = threadIdx.x; i < nbuck; i += 256)
        cursor[i] = cmat[(size_t)i * nblk + k];
    __syncthreads();
    const int base = k * EPB;
    const int end = min(base + EPB, E);
    for (int e = base + threadIdx.x; e < end; e += 256) {
        const int d = dst[e];
        const int b = d >> 6;
        const int pos = atomicAdd(&cursor[b], 1);
        ebuck[pos] = make_uint2(((unsigned)src[e] << 6) | (unsigned)(d & 63),
                                __float_as_uint(ew[e]));
    }
}

// ---------------- phase 3: per-node offs (LDS hist + wave scan) + within-bucket sort ----------------
__global__ __launch_bounds__(256) void sort2_kernel(
    const uint2* __restrict__ ebuck, const int* __restrict__ cmat,
    int* __restrict__ offs, uint2* __restrict__ ecsr,
    int N, int nblk, int nbuck, int E)
{
    __shared__ int cnt[64];
    __shared__ int cur[64];
    const int b = blockIdx.x;
    const int node0 = b << 6;
    const int nn = min(64, N - node0);
    const int j0 = cmat[(size_t)b * nblk];
    const int j1 = (b + 1 < nbuck) ? cmat[(size_t)(b + 1) * nblk] : E;

    if (threadIdx.x < 64) cnt[threadIdx.x] = 0;
    __syncthreads();
    for (int j = j0 + (int)threadIdx.x; j < j1; j += 256)
        atomicAdd(&cnt[ebuck[j].x & 63u], 1);
    __syncthreads();

    if (threadIdx.x < 64) {            // single wave: wave-synchronous scan
        const int myv = cnt[threadIdx.x];
        int v = myv;
#pragma unroll
        for (int d = 1; d < 64; d <<= 1) {
            const int t = __shfl_up(v, d, 64);
            if ((int)threadIdx.x >= d) v += t;
        }
        const int base = j0 + v - myv;   // exclusive
        cur[threadIdx.x] = base;
        if ((int)threadIdx.x < nn) offs[node0 + threadIdx.x] = base;
        if (threadIdx.x == 0 && b == nbuck - 1) offs[N] = E;
    }
    __syncthreads();

    for (int j = j0 + (int)threadIdx.x; j < j1; j += 256) {
        const uint2 ed = ebuck[j];
        const int pos = atomicAdd(&cur[ed.x & 63u], 1);
        ecsr[pos] = make_uint2(ed.x >> 6, ed.y);
    }
}

// ---------------- fused gather-aggregate (bf16 S) + bias + relu (fp32 out) ----------------
template <int D, int LOGT, bool RELU>
__global__ __launch_bounds__(256) void gather_agg_kernel(
    const unsigned short* __restrict__ S, const int* __restrict__ offs,
    const uint2* __restrict__ ecsr,
    const float* __restrict__ bias, float* __restrict__ out, int N)
{
    const int TPN = 1 << LOGT;
    const int gid = blockIdx.x * 256 + threadIdx.x;
    const int node = gid >> LOGT;
    if (node >= N) return;
    const int lane = gid & (TPN - 1);
    const int c8 = lane << 3;

    const int j0 = offs[node];
    const int j1 = offs[node + 1];

    float acc[8];
#pragma unroll
    for (int c = 0; c < 8; ++c) acc[c] = 0.f;

    int jb = j0;
    // full chunks: compile-time trip count -> wide load issue
    for (; jb + TPN <= j1; jb += TPN) {
        const uint2 p = ecsr[jb + lane];
        const int myc = (int)p.x;
        const float myw = __uint_as_float(p.y);
#pragma unroll
        for (int t = 0; t < TPN; ++t) {
            const int s = __shfl(myc, t, TPN);
            const float w = __shfl(myw, t, TPN);
            const uint4 v = *(const uint4*)&S[(size_t)s * D + c8];
#pragma unroll
            for (int q = 0; q < 4; ++q) {
                const unsigned int u = (&v.x)[q];
                acc[q * 2 + 0] += w * __uint_as_float(u << 16);
                acc[q * 2 + 1] += w * __uint_as_float(u & 0xffff0000u);
            }
        }
    }
    if (jb < j1) {
        const int j = jb + lane;
        int myc = 0;
        float myw = 0.f;
        if (j < j1) {
            const uint2 p = ecsr[j];
            myc = (int)p.x;
            myw = __uint_as_float(p.y);
        }
        const int cnt = j1 - jb;
        for (int t = 0; t < cnt; ++t) {
            const int s = __shfl(myc, t, TPN);
            const float w = __shfl(myw, t, TPN);
            const uint4 v = *(const uint4*)&S[(size_t)s * D + c8];
#pragma unroll
            for (int q = 0; q < 4; ++q) {
                const unsigned int u = (&v.x)[q];
                acc[q * 2 + 0] += w * __uint_as_float(u << 16);
                acc[q * 2 + 1] += w * __uint_as_float(u & 0xffff0000u);
            }
        }
    }

#pragma unroll
    for (int c = 0; c < 8; ++c) {
        float v = acc[c] + bias[c8 + c];
        if (RELU) v = fmaxf(v, 0.f);
        acc[c] = v;
    }
    float4* op = (float4*)&out[(size_t)node * D + c8];
    op[0] = make_float4(acc[0], acc[1], acc[2], acc[3]);
    op[1] = make_float4(acc[4], acc[5], acc[6], acc[7]);
}

extern "C" void kernel_launch(void* const* d_in, const int* in_sizes, int n_in,
                              void* d_out, int out_size, void* d_ws, size_t ws_size,
                              hipStream_t stream)
{
    const float* x    = (const float*)d_in[0];
    const int*   esrc = (const int*)  d_in[1];
    const int*   edst = (const int*)  d_in[2];
    const float* ew   = (const float*)d_in[3];
    const float* W1   = (const float*)d_in[4];
    const float* b1   = (const float*)d_in[5];
    const float* W2   = (const float*)d_in[6];
    const float* b2   = (const float*)d_in[7];
    const float* W3   = (const float*)d_in[8];
    const float* b3   = (const float*)d_in[9];

    const int N = in_sizes[0] / 256;   // 100000
    const int E = in_sizes[1];         // 1600000

    const int nbuck = (N + 63) >> 6;               // 1563
    const int nblk = (E + EPB - 1) / EPB;          // 196
    const int L = nbuck * nblk;

    // workspace layout
    unsigned short* Sb = (unsigned short*)d_ws;            // N*128 bf16 support
    float* H   = (float*)(Sb + (size_t)N * 128);           // N*128 fp32 hidden
    unsigned short* WT1 = (unsigned short*)(H + (size_t)N * 128);
    unsigned short* WT2 = WT1 + 256 * 128;
    unsigned short* WT3 = WT2 + 128 * 64;
    uint2* ebuck = (uint2*)(WT3 + 64 * 64);                // E bucket-sorted
    uint2* ecsr  = ebuck + E;                              // E node-sorted (src, w)
    int* offs   = (int*)(ecsr + E);                        // N+1 (pad 4)
    int* cmat   = offs + N + 4;                            // nbuck*nblk
    int* psum   = cmat + ((L + 3) & ~3);                   // up to 1024
    float* out  = (float*)d_out;

    const dim3 blk(256);
    const int mblocks = (N + 127) / 128;                   // 782

    // ---- prep: weights + bucket sort + per-node offs ----
    wt_kernel<<<(45056 + 255) / 256, blk, 0, stream>>>(W1, W2, W3, WT1, WT2, WT3);
    count_kernel<<<nblk, blk, 0, stream>>>(edst, cmat, E, nblk, nbuck);
    scanA_kernel<<<(L + 1023) / 1024, blk, 0, stream>>>(cmat, psum, L);
    scanB_kernel<<<1, 1024, 0, stream>>>(psum, (L + 1023) / 1024);
    scanC_kernel<<<(L + 255) / 256, blk, 0, stream>>>(cmat, psum, L);
    place_kernel<<<nblk, blk, 0, stream>>>(esrc, edst, ew, cmat, ebuck, E, nblk, nbuck);
    sort2_kernel<<<nbuck, blk, 0, stream>>>(ebuck, cmat, offs, ecsr, N, nblk, nbuck, E);

    // ---- layer 1: 256 -> 128 ----
    mfma_gemm_kernel<128><<<mblocks, blk, 0, stream>>>(x, WT1, Sb, N, 256);
    gather_agg_kernel<128, 4, true><<<((N * 16) + 255) / 256, blk, 0, stream>>>(
        Sb, offs, ecsr, b1, H, N);

    // ---- layer 2: 128 -> 64 ----
    mfma_gemm_kernel<64><<<mblocks, blk, 0, stream>>>(H, WT2, Sb, N, 128);
    gather_agg_kernel<64, 3, true><<<((N * 8) + 255) / 256, blk, 0, stream>>>(
        Sb, offs, ecsr, b2, H, N);

    // ---- layer 3: 64 -> 64 ----
    mfma_gemm_kernel<64><<<mblocks, blk, 0, stream>>>(H, WT3, Sb, N, 64);
    gather_agg_kernel<64, 3, false><<<((N * 8) + 255) / 256, blk, 0, stream>>>(
        Sb, offs, ecsr, b3, out, N);
}